// Round 11
// baseline (117.969 us; speedup 1.0000x reference)
//
#include <hip/hip_runtime.h>
#include <hip/hip_bf16.h>
#include <cstdint>

#define IN_F   1024
#define OUT_F  1024
#define KTOT   9216
#define BATCH  4096

#define NTK    288            // total BK=32 K-steps
#define PSTEP  8192           // bytes per (128-row panel, kt32) fragment block
#define SLOT_B 32768          // ring slot: A 16K | B 16K
#define BM 256
#define BN 256

typedef __attribute__((ext_vector_type(8))) __bf16 bf16x8;
typedef __attribute__((ext_vector_type(4))) float  f32x4;
typedef __attribute__((ext_vector_type(8))) short  short8v;

typedef __attribute__((address_space(1))) const uint32_t gu32;
typedef __attribute__((address_space(3))) uint32_t       lu32;

__device__ __forceinline__ void gl_lds16(const void* g, void* l) {
    __builtin_amdgcn_global_load_lds((gu32*)g, (lu32*)l, 16, 0, 0);
}

__device__ __forceinline__ unsigned short f2bf(float f) {
    unsigned int u = __builtin_bit_cast(unsigned int, f);
    return (unsigned short)((u + 0x7fffu + ((u >> 16) & 1u)) >> 16);
}

__device__ __forceinline__ float knot(int i) { return 0.4f * (float)i - 2.2f; }

// ---------------------------------------------------------------------------
// Fragment-major layout (both Act and Wb):
//   byte = ((panel128 * 288 + kt32) * 8192) + g*1024 + (kgrp*16 + frow)*16
// One 1KB unit = one MFMA fragment (64 lanes x 16B, contiguous).
// ---------------------------------------------------------------------------

// ---------------------------------------------------------------------------
// Prep (r10-verbatim). [0,512): Act. [512,1024): Wb base. [1024,5120): spline.
// ---------------------------------------------------------------------------
__global__ __launch_bounds__(256)
void build_all_kernel(const float* __restrict__ x,
                      const float* __restrict__ base_w,
                      const float* __restrict__ spline_w,
                      const float* __restrict__ scaler,
                      unsigned short* __restrict__ Act,
                      unsigned short* __restrict__ Wb) {
    const int bid = blockIdx.x;
    const int tid = threadIdx.x;
    if (bid < 512) {
        __shared__ float xs[128][65];
        const int mb = bid >> 4;
        const int p  = bid & 15;

        const float* xbase = x + (size_t)mb * 128 * IN_F + p * 64;
        #pragma unroll
        for (int i = 0; i < 32; ++i) {
            const int f = i * 256 + tid;
            const int rr = f >> 6, c = f & 63;
            xs[rr][c] = xbase[(size_t)rr * IN_F + c];
        }
        __syncthreads();

        char* outS = (char*)Act + (size_t)(mb * 144 + p) * 16384;
        char* outB = (char*)Act + (size_t)(mb * 144 + 16 + p * 8) * 16384;

        const float r1 = 1.0f / (0.4f + 1e-8f);
        const float r2 = 1.0f / (0.8f + 1e-8f);
        const float r3 = 1.0f / (1.2f + 1e-8f);

        #pragma unroll
        for (int it = 0; it < 4; ++it) {
            const int ch = it * 256 + tid;
            const int kp = ch >> 9, g = (ch >> 6) & 7, kg = (ch >> 4) & 3, fr = ch & 15;
            const int b = g * 16 + fr;
            const int c0 = kp * 32 + kg * 8;
            short8v v;
            #pragma unroll
            for (int u = 0; u < 8; ++u) {
                const float xv = xs[b][c0 + u];
                v[u] = (short)f2bf(xv * __frcp_rn(1.0f + __expf(-xv)));
            }
            *(short8v*)(outS + kp * 8192 + g * 1024 + kg * 256 + fr * 16) = v;
        }

        #pragma unroll
        for (int it = 0; it < 32; ++it) {
            const int ch  = it * 256 + tid;
            const int ktl = ch >> 10;
            const int rest = ch & 1023;
            const int kp = rest >> 9, g = (rest >> 6) & 7, kg = (rest >> 4) & 3, fr = rest & 15;
            const int b  = g * 16 + fr;
            const int jc = 8 * ktl + 4 * kp + kg;
            const float xv = xs[b][jc];

            float bas[11];
            #pragma unroll
            for (int t = 0; t < 11; ++t)
                bas[t] = (xv >= knot(t) && xv < knot(t + 1)) ? 1.0f : 0.0f;
            #pragma unroll
            for (int t = 0; t < 10; ++t)
                bas[t] = (xv - knot(t)) * r1 * bas[t] + (knot(t + 2) - xv) * r1 * bas[t + 1];
            #pragma unroll
            for (int t = 0; t < 9; ++t)
                bas[t] = (xv - knot(t)) * r2 * bas[t] + (knot(t + 3) - xv) * r2 * bas[t + 1];
            #pragma unroll
            for (int t = 0; t < 8; ++t)
                bas[t] = (xv - knot(t)) * r3 * bas[t] + (knot(t + 4) - xv) * r3 * bas[t + 1];

            short8v v;
            #pragma unroll
            for (int c = 0; c < 8; ++c) v[c] = (short)f2bf(bas[c]);
            *(short8v*)(outB + (size_t)ktl * 16384
                        + kp * 8192 + g * 1024 + kg * 256 + fr * 16) = v;
        }
    } else if (bid < 1024) {
        const int bw = bid - 512;
        const int nb = bw >> 6, kt = (bw >> 1) & 31, half = bw & 1;
        const int g = half * 4 + (tid >> 6);
        const int lane = tid & 63;
        const int kgrp = lane >> 4, frow = lane & 15;
        const int oo = nb * 128 + g * 16 + frow;
        const int jb = kt * 32 + kgrp * 8;

        const float4 w0 = *(const float4*)(base_w + (size_t)oo * 1024 + jb);
        const float4 w1 = *(const float4*)(base_w + (size_t)oo * 1024 + jb + 4);
        short8v v;
        v[0] = (short)f2bf(w0.x); v[1] = (short)f2bf(w0.y);
        v[2] = (short)f2bf(w0.z); v[3] = (short)f2bf(w0.w);
        v[4] = (short)f2bf(w1.x); v[5] = (short)f2bf(w1.y);
        v[6] = (short)f2bf(w1.z); v[7] = (short)f2bf(w1.w);
        *(short8v*)((char*)Wb + (size_t)(nb * NTK + kt) * PSTEP
                    + g * 1024 + lane * 16) = v;
    } else {
        const int bw = bid - 1024;
        const int nb = bw >> 9, kt2 = (bw >> 1) & 255, half = bw & 1;
        const int kt = 32 + kt2;
        const int g = half * 4 + (tid >> 6);
        const int lane = tid & 63;
        const int kgrp = lane >> 4, frow = lane & 15;
        const int oo = nb * 128 + g * 16 + frow;
        const int j  = kt2 * 4 + kgrp;

        const float s = scaler[(size_t)oo * 1024 + j];
        const float* sp = spline_w + ((size_t)oo * 1024 + j) * 8;
        const float4 w0 = *(const float4*)sp;
        const float4 w1 = *(const float4*)(sp + 4);
        short8v v;
        v[0] = (short)f2bf(w0.x * s); v[1] = (short)f2bf(w0.y * s);
        v[2] = (short)f2bf(w0.z * s); v[3] = (short)f2bf(w0.w * s);
        v[4] = (short)f2bf(w1.x * s); v[5] = (short)f2bf(w1.y * s);
        v[6] = (short)f2bf(w1.z * s); v[7] = (short)f2bf(w1.w * s);
        *(short8v*)((char*)Wb + (size_t)(nb * NTK + kt) * PSTEP
                    + g * 1024 + lane * 16) = v;
    }
}

// ---------------------------------------------------------------------------
// 256x256 GEMM, BK=32, adaptive split-K. r10 structure + m201-style 2-phase
// interleave per K-step: phase = {ds_read half the frags | 2 gl_lds(kt+3) ->
// barrier -> lgkmcnt(0) -> setprio -> 16 MFMA -> setprio -> barrier}.
// vmcnt(8) once per step at phase-B end (drains tile kt+1 for next step's
// reads). Drain arithmetic: prologue stages tiles 0..2 (12 ops); steady state
// 12 outstanding at the wait -> vmcnt(8) drains the oldest tile. Tail 4 -> 0.
// Slot-reuse safety: each phase's lgkm(0) precedes its closing barrier; the
// restage of slot (kt-1)&3 issues only after that barrier.
// ---------------------------------------------------------------------------
__global__ __launch_bounds__(512)
void gemm_kernel(const unsigned short* __restrict__ Act,
                 const unsigned short* __restrict__ Wb,
                 float* __restrict__ C, float* __restrict__ P,
                 int ksteps) {
    __shared__ char Sm[4 * SLOT_B];   // 128 KB

    const int tid  = threadIdx.x;
    const int lane = tid & 63;
    const int wave = tid >> 6;
    const int wr   = wave >> 1;       // 0..3 (64-row slice)
    const int wn   = wave & 1;        // 0..1 (128-col half)

    const int bid  = blockIdx.x;
    const int xcd  = bid & 7;
    const int rr_  = bid >> 3;
    const int mtile = xcd * 2 + (rr_ & 1);   // A panels XCD-private
    const int ntile = (rr_ >> 1) & 3;
    const int s     = rr_ >> 3;              // split-K index

    const int frow = lane & 15;
    const int kgrp = lane >> 4;

    float* Cout = (s == 0) ? C : (P + (size_t)(s - 1) * ((size_t)BATCH * OUT_F));

    f32x4 acc[4][8] = {};             // 128 regs
    bf16x8 aF[4], bF[8];              // 48 regs

    const int o = tid * 16;
    const size_t ktbase = (size_t)s * ksteps;

    const char* aLo = (const char*)Act + ((size_t)(mtile * 2) * NTK + ktbase) * PSTEP + o;
    const char* aHi = aLo + (size_t)NTK * PSTEP;
    const char* bLo = (const char*)Wb  + ((size_t)(ntile * 2) * NTK + ktbase) * PSTEP + o;
    const char* bHi = bLo + (size_t)NTK * PSTEP;

    #define STAGE_FULL(kt, sl) do {                                  \
        const size_t kk = (size_t)(kt) * PSTEP;                      \
        char* d = Sm + (size_t)(sl) * SLOT_B + o;                    \
        gl_lds16(aLo + kk, d);                                       \
        gl_lds16(aHi + kk, d + 8192);                                \
        gl_lds16(bLo + kk, d + 16384);                               \
        gl_lds16(bHi + kk, d + 24576);                               \
    } while (0)

    #define RD_A(bA_) do {                                                    \
        _Pragma("unroll")                                                     \
        for (int m = 0; m < 4; ++m)                                           \
            aF[m] = *(const bf16x8*)((bA_) + (wr * 4 + m) * 1024 + lane * 16);\
    } while (0)

    #define RD_B(bB_, n0_, n1_) do {                                          \
        _Pragma("unroll")                                                     \
        for (int n = (n0_); n < (n1_); ++n)                                   \
            bF[n] = *(const bf16x8*)((bB_) + (wn * 8 + n) * 1024 + lane * 16);\
    } while (0)

    #define MFMA_HALF(n0_, n1_) do {                                          \
        __builtin_amdgcn_s_barrier();                                         \
        asm volatile("s_waitcnt lgkmcnt(0)" ::: "memory");                    \
        __builtin_amdgcn_s_setprio(1);                                        \
        _Pragma("unroll")                                                     \
        for (int m = 0; m < 4; ++m)                                           \
            _Pragma("unroll")                                                 \
            for (int n = (n0_); n < (n1_); ++n)                               \
                acc[m][n] = __builtin_amdgcn_mfma_f32_16x16x32_bf16(          \
                                aF[m], bF[n], acc[m][n], 0, 0, 0);            \
        __builtin_amdgcn_s_setprio(0);                                        \
    } while (0)

    // ---- prologue: tiles 0..2 staged; land tile 0 -------------------------
    STAGE_FULL(0, 0);
    STAGE_FULL(1, 1);
    STAGE_FULL(2, 2);
    asm volatile("s_waitcnt vmcnt(8)" ::: "memory");
    __builtin_amdgcn_s_barrier();

    // ---- main: kt = 0..ksteps-4 (stage kt+3, steady vmcnt(8)) -------------
    for (int kt = 0; kt <= ksteps - 4; ++kt) {
        const char* bA_ = Sm + (size_t)(kt & 3) * SLOT_B;
        const char* bB_ = bA_ + 16384;
        const size_t kk3 = (size_t)(kt + 3) * PSTEP;
        char* d3 = Sm + (size_t)((kt + 3) & 3) * SLOT_B + o;

        // phase A
        RD_A(bA_); RD_B(bB_, 0, 4);
        gl_lds16(aLo + kk3, d3);
        gl_lds16(aHi + kk3, d3 + 8192);
        MFMA_HALF(0, 4);
        __builtin_amdgcn_s_barrier();

        // phase B
        RD_B(bB_, 4, 8);
        gl_lds16(bLo + kk3, d3 + 16384);
        gl_lds16(bHi + kk3, d3 + 24576);
        MFMA_HALF(4, 8);
        asm volatile("s_waitcnt vmcnt(8)" ::: "memory");   // tile kt+1 landed
        __builtin_amdgcn_s_barrier();
    }

    // ---- tail: kt = ksteps-3 (no stage, vmcnt(4)) -------------------------
    {
        const int kt = ksteps - 3;
        const char* bA_ = Sm + (size_t)(kt & 3) * SLOT_B;
        const char* bB_ = bA_ + 16384;
        RD_A(bA_); RD_B(bB_, 0, 4);
        MFMA_HALF(0, 4);
        __builtin_amdgcn_s_barrier();
        RD_B(bB_, 4, 8);
        MFMA_HALF(4, 8);
        asm volatile("s_waitcnt vmcnt(4)" ::: "memory");   // tile ksteps-2
        __builtin_amdgcn_s_barrier();
    }
    // ---- kt = ksteps-2 (no stage, vmcnt(0)) -------------------------------
    {
        const int kt = ksteps - 2;
        const char* bA_ = Sm + (size_t)(kt & 3) * SLOT_B;
        const char* bB_ = bA_ + 16384;
        RD_A(bA_); RD_B(bB_, 0, 4);
        MFMA_HALF(0, 4);
        __builtin_amdgcn_s_barrier();
        RD_B(bB_, 4, 8);
        MFMA_HALF(4, 8);
        asm volatile("s_waitcnt vmcnt(0)" ::: "memory");   // tile ksteps-1
        __builtin_amdgcn_s_barrier();
    }
    // ---- kt = ksteps-1 (no stage, no vmcnt) -------------------------------
    {
        const int kt = ksteps - 1;
        const char* bA_ = Sm + (size_t)(kt & 3) * SLOT_B;
        const char* bB_ = bA_ + 16384;
        RD_A(bA_); RD_B(bB_, 0, 4);
        MFMA_HALF(0, 4);
        __builtin_amdgcn_s_barrier();
        RD_B(bB_, 4, 8);
        MFMA_HALF(4, 8);
    }

    // ---- epilogue: direct store; C/D map col=lane&15, row=(lane>>4)*4+reg --
    const int m0 = mtile * BM, n0 = ntile * BN;
    #pragma unroll
    for (int m = 0; m < 4; ++m) {
        const int row = m0 + wr * 64 + m * 16 + kgrp * 4;
        #pragma unroll
        for (int n = 0; n < 8; ++n) {
            const int col = n0 + wn * 128 + n * 16 + frow;
            float* cp = Cout + (size_t)row * OUT_F + col;
            #pragma unroll
            for (int q = 0; q < 4; ++q)
                cp[(size_t)q * OUT_F] = acc[m][n][q];
        }
    }
    #undef STAGE_FULL
    #undef RD_A
    #undef RD_B
    #undef MFMA_HALF
}

// ---------------------------------------------------------------------------
__global__ __launch_bounds__(256)
void add_kernel(float* __restrict__ out, const float* __restrict__ P, int np) {
    const size_t i = (size_t)blockIdx.x * 256 + threadIdx.x;   // float4 index
    float4 a = ((const float4*)out)[i];
    for (int k = 0; k < np; ++k) {
        float4 b = ((const float4*)(P + (size_t)k * ((size_t)BATCH * OUT_F)))[i];
        a.x += b.x; a.y += b.y; a.z += b.z; a.w += b.w;
    }
    ((float4*)out)[i] = a;
}

// ---------------------------------------------------------------------------
extern "C" void kernel_launch(void* const* d_in, const int* in_sizes, int n_in,
                              void* d_out, int out_size, void* d_ws, size_t ws_size,
                              hipStream_t stream) {
    const float* x        = (const float*)d_in[0];
    const float* base_w   = (const float*)d_in[1];
    const float* spline_w = (const float*)d_in[2];
    const float* scaler   = (const float*)d_in[3];
    float* out = (float*)d_out;

    const size_t act_b = (size_t)BATCH * KTOT * 2;        // 75.5 MB
    const size_t wb_b  = (size_t)OUT_F * KTOT * 2;        // 18.9 MB
    const size_t ps    = (size_t)BATCH * OUT_F * 4;       // 16.8 MB per partial
    if (ws_size < act_b + wb_b) return;

    unsigned short* Act = (unsigned short*)d_ws;
    unsigned short* Wb  = (unsigned short*)((char*)d_ws + act_b);
    float*          P   = (float*)((char*)d_ws + act_b + wb_b);

    size_t avail = ws_size - act_b - wb_b;
    int np = (int)(avail / ps); if (np > 3) np = 3; if (np < 0) np = 0;
    const int nsplit = np + 1;             // 1,2,3,4 all divide 288
    const int ksteps = NTK / nsplit;

    build_all_kernel<<<5120, 256, 0, stream>>>(x, base_w, spline_w, scaler, Act, Wb);
    gemm_kernel<<<64 * nsplit, 512, 0, stream>>>(Act, Wb, out, P, ksteps);
    if (np > 0)
        add_kernel<<<(BATCH * OUT_F) / (256 * 4), 256, 0, stream>>>(out, P, np);
}

// Round 12
// 114.483 us; speedup vs baseline: 1.0304x; 1.0304x over previous
//
#include <hip/hip_runtime.h>
#include <hip/hip_bf16.h>
#include <cstdint>

#define IN_F   1024
#define OUT_F  1024
#define KTOT   9216
#define BATCH  4096

#define NTK    288            // total BK=32 K-steps
#define PSTEP  8192           // bytes per (128-row panel, kt32) fragment block
#define SLOT_B 32768          // ring slot: A 16K | B 16K
#define BM 256
#define BN 256

typedef __attribute__((ext_vector_type(8))) __bf16 bf16x8;
typedef __attribute__((ext_vector_type(4))) float  f32x4;
typedef __attribute__((ext_vector_type(8))) short  short8v;

typedef __attribute__((address_space(1))) const uint32_t gu32;
typedef __attribute__((address_space(3))) uint32_t       lu32;

__device__ __forceinline__ void gl_lds16(const void* g, void* l) {
    __builtin_amdgcn_global_load_lds((gu32*)g, (lu32*)l, 16, 0, 0);
}

__device__ __forceinline__ unsigned short f2bf(float f) {
    unsigned int u = __builtin_bit_cast(unsigned int, f);
    return (unsigned short)((u + 0x7fffu + ((u >> 16) & 1u)) >> 16);
}

__device__ __forceinline__ float knot(int i) { return 0.4f * (float)i - 2.2f; }

// ---------------------------------------------------------------------------
// Fragment-major layout (both Act and Wb):
//   byte = ((panel128 * 288 + kt32) * 8192) + g*1024 + (kgrp*16 + frow)*16
// One 1KB unit = one MFMA fragment (64 lanes x 16B, contiguous).
// ---------------------------------------------------------------------------

// ---------------------------------------------------------------------------
// Prep (r10-verbatim). [0,512): Act. [512,1024): Wb base. [1024,5120): spline.
// ---------------------------------------------------------------------------
__global__ __launch_bounds__(256)
void build_all_kernel(const float* __restrict__ x,
                      const float* __restrict__ base_w,
                      const float* __restrict__ spline_w,
                      const float* __restrict__ scaler,
                      unsigned short* __restrict__ Act,
                      unsigned short* __restrict__ Wb) {
    const int bid = blockIdx.x;
    const int tid = threadIdx.x;
    if (bid < 512) {
        __shared__ float xs[128][65];
        const int mb = bid >> 4;
        const int p  = bid & 15;

        const float* xbase = x + (size_t)mb * 128 * IN_F + p * 64;
        #pragma unroll
        for (int i = 0; i < 32; ++i) {
            const int f = i * 256 + tid;
            const int rr = f >> 6, c = f & 63;
            xs[rr][c] = xbase[(size_t)rr * IN_F + c];
        }
        __syncthreads();

        char* outS = (char*)Act + (size_t)(mb * 144 + p) * 16384;
        char* outB = (char*)Act + (size_t)(mb * 144 + 16 + p * 8) * 16384;

        const float r1 = 1.0f / (0.4f + 1e-8f);
        const float r2 = 1.0f / (0.8f + 1e-8f);
        const float r3 = 1.0f / (1.2f + 1e-8f);

        #pragma unroll
        for (int it = 0; it < 4; ++it) {
            const int ch = it * 256 + tid;
            const int kp = ch >> 9, g = (ch >> 6) & 7, kg = (ch >> 4) & 3, fr = ch & 15;
            const int b = g * 16 + fr;
            const int c0 = kp * 32 + kg * 8;
            short8v v;
            #pragma unroll
            for (int u = 0; u < 8; ++u) {
                const float xv = xs[b][c0 + u];
                v[u] = (short)f2bf(xv * __frcp_rn(1.0f + __expf(-xv)));
            }
            *(short8v*)(outS + kp * 8192 + g * 1024 + kg * 256 + fr * 16) = v;
        }

        #pragma unroll
        for (int it = 0; it < 32; ++it) {
            const int ch  = it * 256 + tid;
            const int ktl = ch >> 10;
            const int rest = ch & 1023;
            const int kp = rest >> 9, g = (rest >> 6) & 7, kg = (rest >> 4) & 3, fr = rest & 15;
            const int b  = g * 16 + fr;
            const int jc = 8 * ktl + 4 * kp + kg;
            const float xv = xs[b][jc];

            float bas[11];
            #pragma unroll
            for (int t = 0; t < 11; ++t)
                bas[t] = (xv >= knot(t) && xv < knot(t + 1)) ? 1.0f : 0.0f;
            #pragma unroll
            for (int t = 0; t < 10; ++t)
                bas[t] = (xv - knot(t)) * r1 * bas[t] + (knot(t + 2) - xv) * r1 * bas[t + 1];
            #pragma unroll
            for (int t = 0; t < 9; ++t)
                bas[t] = (xv - knot(t)) * r2 * bas[t] + (knot(t + 3) - xv) * r2 * bas[t + 1];
            #pragma unroll
            for (int t = 0; t < 8; ++t)
                bas[t] = (xv - knot(t)) * r3 * bas[t] + (knot(t + 4) - xv) * r3 * bas[t + 1];

            short8v v;
            #pragma unroll
            for (int c = 0; c < 8; ++c) v[c] = (short)f2bf(bas[c]);
            *(short8v*)(outB + (size_t)ktl * 16384
                        + kp * 8192 + g * 1024 + kg * 256 + fr * 16) = v;
        }
    } else if (bid < 1024) {
        const int bw = bid - 512;
        const int nb = bw >> 6, kt = (bw >> 1) & 31, half = bw & 1;
        const int g = half * 4 + (tid >> 6);
        const int lane = tid & 63;
        const int kgrp = lane >> 4, frow = lane & 15;
        const int oo = nb * 128 + g * 16 + frow;
        const int jb = kt * 32 + kgrp * 8;

        const float4 w0 = *(const float4*)(base_w + (size_t)oo * 1024 + jb);
        const float4 w1 = *(const float4*)(base_w + (size_t)oo * 1024 + jb + 4);
        short8v v;
        v[0] = (short)f2bf(w0.x); v[1] = (short)f2bf(w0.y);
        v[2] = (short)f2bf(w0.z); v[3] = (short)f2bf(w0.w);
        v[4] = (short)f2bf(w1.x); v[5] = (short)f2bf(w1.y);
        v[6] = (short)f2bf(w1.z); v[7] = (short)f2bf(w1.w);
        *(short8v*)((char*)Wb + (size_t)(nb * NTK + kt) * PSTEP
                    + g * 1024 + lane * 16) = v;
    } else {
        const int bw = bid - 1024;
        const int nb = bw >> 9, kt2 = (bw >> 1) & 255, half = bw & 1;
        const int kt = 32 + kt2;
        const int g = half * 4 + (tid >> 6);
        const int lane = tid & 63;
        const int kgrp = lane >> 4, frow = lane & 15;
        const int oo = nb * 128 + g * 16 + frow;
        const int j  = kt2 * 4 + kgrp;

        const float s = scaler[(size_t)oo * 1024 + j];
        const float* sp = spline_w + ((size_t)oo * 1024 + j) * 8;
        const float4 w0 = *(const float4*)sp;
        const float4 w1 = *(const float4*)(sp + 4);
        short8v v;
        v[0] = (short)f2bf(w0.x * s); v[1] = (short)f2bf(w0.y * s);
        v[2] = (short)f2bf(w0.z * s); v[3] = (short)f2bf(w0.w * s);
        v[4] = (short)f2bf(w1.x * s); v[5] = (short)f2bf(w1.y * s);
        v[6] = (short)f2bf(w1.z * s); v[7] = (short)f2bf(w1.w * s);
        *(short8v*)((char*)Wb + (size_t)(nb * NTK + kt) * PSTEP
                    + g * 1024 + lane * 16) = v;
    }
}

// ---------------------------------------------------------------------------
// 256x256 GEMM, BK=32, adaptive split-K. r10 ring-4/depth-2 staging +
// register fragment DOUBLE-BUFFER (r5 mechanism at 256^2): at iter kt, issue
// ds_reads of tile kt+1 into the spare frag set, then run tile kt's 32 MFMAs
// on the current set — no lgkm dependency at MFMA issue (compiler sees the
// reg-deps), so the DS pipe (~1140 cyc/step) overlaps the MFMA pipe
// (1242 cyc/step) instead of serializing (r10/r11: 2417 cyc/step).
// Safety: reads of slot s in region [bar_k,bar_k+1] drain before each wave's
// MFMA in the next region, hence before any wave reaches bar_k+2; restage of
// that slot issues only after bar_k+2. vmcnt(4) pre-barrier = tile kt+1
// landed (tile kt+2's 4 ops outstanding). sched_barrier(0) pins reads after
// the s_barrier (compile-time only).
// ---------------------------------------------------------------------------
__global__ __launch_bounds__(512)
void gemm_kernel(const unsigned short* __restrict__ Act,
                 const unsigned short* __restrict__ Wb,
                 float* __restrict__ C, float* __restrict__ P,
                 int ksteps) {
    __shared__ char Sm[4 * SLOT_B];   // 128 KB

    const int tid  = threadIdx.x;
    const int lane = tid & 63;
    const int wave = tid >> 6;
    const int wr   = wave >> 1;       // 0..3 (64-row slice)
    const int wn   = wave & 1;        // 0..1 (128-col half)

    const int bid  = blockIdx.x;
    const int xcd  = bid & 7;
    const int rr_  = bid >> 3;
    const int mtile = xcd * 2 + (rr_ & 1);   // A panels XCD-private
    const int ntile = (rr_ >> 1) & 3;
    const int s     = rr_ >> 3;              // split-K index

    const int frow = lane & 15;
    const int kgrp = lane >> 4;

    float* Cout = (s == 0) ? C : (P + (size_t)(s - 1) * ((size_t)BATCH * OUT_F));

    f32x4 acc[4][8] = {};             // accumulators (AGPR side)
    bf16x8 aR0[4], bR0[8], aR1[4], bR1[8];   // frag double-buffer

    const int o = tid * 16;
    const size_t ktbase = (size_t)s * ksteps;

    const char* aLo = (const char*)Act + ((size_t)(mtile * 2) * NTK + ktbase) * PSTEP + o;
    const char* aHi = aLo + (size_t)NTK * PSTEP;
    const char* bLo = (const char*)Wb  + ((size_t)(ntile * 2) * NTK + ktbase) * PSTEP + o;
    const char* bHi = bLo + (size_t)NTK * PSTEP;

    #define STAGE(kt, sl) do {                                       \
        const size_t kk = (size_t)(kt) * PSTEP;                      \
        char* d = Sm + (size_t)(sl) * SLOT_B + o;                    \
        gl_lds16(aLo + kk, d);                                       \
        gl_lds16(aHi + kk, d + 8192);                                \
        gl_lds16(bLo + kk, d + 16384);                               \
        gl_lds16(bHi + kk, d + 24576);                               \
    } while (0)

    #define RD(sl, AB, BB) do {                                               \
        const char* bA_ = Sm + (size_t)(sl) * SLOT_B;                         \
        const char* bB_ = bA_ + 16384;                                        \
        _Pragma("unroll")                                                     \
        for (int m = 0; m < 4; ++m)                                           \
            (AB)[m] = *(const bf16x8*)(bA_ + (wr * 4 + m) * 1024 + lane * 16);\
        _Pragma("unroll")                                                     \
        for (int n = 0; n < 8; ++n)                                           \
            (BB)[n] = *(const bf16x8*)(bB_ + (wn * 8 + n) * 1024 + lane * 16);\
    } while (0)

    #define MFMA32(AB, BB) do {                                               \
        __builtin_amdgcn_s_setprio(1);                                        \
        _Pragma("unroll")                                                     \
        for (int m = 0; m < 4; ++m)                                           \
            _Pragma("unroll")                                                 \
            for (int n = 0; n < 8; ++n)                                       \
                acc[m][n] = __builtin_amdgcn_mfma_f32_16x16x32_bf16(          \
                                (AB)[m], (BB)[n], acc[m][n], 0, 0, 0);        \
        __builtin_amdgcn_s_setprio(0);                                        \
    } while (0)

    #define SYNC(VM) do {                                                     \
        asm volatile("s_waitcnt vmcnt(" #VM ")" ::: "memory");                \
        __builtin_amdgcn_s_barrier();                                         \
        __builtin_amdgcn_sched_barrier(0);                                    \
    } while (0)

    // ---- prologue: tiles 0,1 staged; land tile 0; preload its frags -------
    STAGE(0, 0);
    STAGE(1, 1);
    SYNC(4);                        // tile 0 landed (tile 1 outstanding)
    RD(0, aR0, bR0);

    // ---- main: 2-step unrolled; kt = 0,2,..,ksteps-4 ----------------------
    #pragma unroll 1
    for (int kt = 0; kt < ksteps - 2; kt += 2) {
        STAGE(kt + 2, (kt + 2) & 3);
        SYNC(4);                    // tile kt+1 landed
        RD((kt + 1) & 3, aR1, bR1); // prefetch next frags (no MFMA dep)
        MFMA32(aR0, bR0);           // tile kt

        STAGE(kt + 3, (kt + 3) & 3);
        SYNC(4);                    // tile kt+2 landed
        RD((kt + 2) & 3, aR0, bR0);
        MFMA32(aR1, bR1);           // tile kt+1
    }

    // ---- tail: tiles ksteps-2, ksteps-1 (aR0 holds ksteps-2 frags) --------
    SYNC(0);                        // tile ksteps-1 landed
    RD((ksteps - 1) & 3, aR1, bR1);
    MFMA32(aR0, bR0);               // tile ksteps-2
    MFMA32(aR1, bR1);               // tile ksteps-1 (compiler inserts lgkm)

    // ---- epilogue: direct store; C/D map col=lane&15, row=(lane>>4)*4+reg --
    const int m0 = mtile * BM, n0 = ntile * BN;
    #pragma unroll
    for (int m = 0; m < 4; ++m) {
        const int row = m0 + wr * 64 + m * 16 + kgrp * 4;
        #pragma unroll
        for (int n = 0; n < 8; ++n) {
            const int col = n0 + wn * 128 + n * 16 + frow;
            float* cp = Cout + (size_t)row * OUT_F + col;
            #pragma unroll
            for (int q = 0; q < 4; ++q)
                cp[(size_t)q * OUT_F] = acc[m][n][q];
        }
    }
    #undef STAGE
    #undef RD
    #undef MFMA32
    #undef SYNC
}

// ---------------------------------------------------------------------------
__global__ __launch_bounds__(256)
void add_kernel(float* __restrict__ out, const float* __restrict__ P, int np) {
    const size_t i = (size_t)blockIdx.x * 256 + threadIdx.x;   // float4 index
    float4 a = ((const float4*)out)[i];
    for (int k = 0; k < np; ++k) {
        float4 b = ((const float4*)(P + (size_t)k * ((size_t)BATCH * OUT_F)))[i];
        a.x += b.x; a.y += b.y; a.z += b.z; a.w += b.w;
    }
    ((float4*)out)[i] = a;
}

// ---------------------------------------------------------------------------
extern "C" void kernel_launch(void* const* d_in, const int* in_sizes, int n_in,
                              void* d_out, int out_size, void* d_ws, size_t ws_size,
                              hipStream_t stream) {
    const float* x        = (const float*)d_in[0];
    const float* base_w   = (const float*)d_in[1];
    const float* spline_w = (const float*)d_in[2];
    const float* scaler   = (const float*)d_in[3];
    float* out = (float*)d_out;

    const size_t act_b = (size_t)BATCH * KTOT * 2;        // 75.5 MB
    const size_t wb_b  = (size_t)OUT_F * KTOT * 2;        // 18.9 MB
    const size_t ps    = (size_t)BATCH * OUT_F * 4;       // 16.8 MB per partial
    if (ws_size < act_b + wb_b) return;

    unsigned short* Act = (unsigned short*)d_ws;
    unsigned short* Wb  = (unsigned short*)((char*)d_ws + act_b);
    float*          P   = (float*)((char*)d_ws + act_b + wb_b);

    size_t avail = ws_size - act_b - wb_b;
    int np = (int)(avail / ps); if (np > 3) np = 3; if (np < 0) np = 0;
    const int nsplit = np + 1;             // 1,2,3,4 all divide 288
    const int ksteps = NTK / nsplit;

    build_all_kernel<<<5120, 256, 0, stream>>>(x, base_w, spline_w, scaler, Act, Wb);
    gemm_kernel<<<64 * nsplit, 512, 0, stream>>>(Act, Wb, out, P, ksteps);
    if (np > 0)
        add_kernel<<<(BATCH * OUT_F) / (256 * 4), 256, 0, stream>>>(out, P, np);
}

// Round 13
// 113.339 us; speedup vs baseline: 1.0409x; 1.0101x over previous
//
#include <hip/hip_runtime.h>
#include <hip/hip_bf16.h>
#include <cstdint>

#define IN_F   1024
#define OUT_F  1024
#define KTOT   9216
#define BATCH  4096

#define NTK    288            // total BK=32 K-steps
#define PSTEP  8192           // bytes per (128-row panel, kt32) fragment block
#define SLOT_B 32768          // ring slot: A 16K | B 16K
#define BM 256
#define BN 256

typedef __attribute__((ext_vector_type(8))) __bf16 bf16x8;
typedef __attribute__((ext_vector_type(4))) float  f32x4;
typedef __attribute__((ext_vector_type(8))) short  short8v;

typedef __attribute__((address_space(1))) const uint32_t gu32;
typedef __attribute__((address_space(3))) uint32_t       lu32;

__device__ __forceinline__ void gl_lds16(const void* g, void* l) {
    __builtin_amdgcn_global_load_lds((gu32*)g, (lu32*)l, 16, 0, 0);
}

__device__ __forceinline__ unsigned short f2bf(float f) {
    unsigned int u = __builtin_bit_cast(unsigned int, f);
    return (unsigned short)((u + 0x7fffu + ((u >> 16) & 1u)) >> 16);
}

__device__ __forceinline__ float knot(int i) { return 0.4f * (float)i - 2.2f; }

// ---------------------------------------------------------------------------
// Fragment-major layout (both Act and Wb):
//   byte = ((panel128 * 288 + kt32) * 8192) + g*1024 + (kgrp*16 + frow)*16
// One 1KB unit = one MFMA fragment (64 lanes x 16B, contiguous).
// ---------------------------------------------------------------------------

// ---------------------------------------------------------------------------
// Prep (r10-verbatim). [0,512): Act. [512,1024): Wb base. [1024,5120): spline.
// ---------------------------------------------------------------------------
__global__ __launch_bounds__(256)
void build_all_kernel(const float* __restrict__ x,
                      const float* __restrict__ base_w,
                      const float* __restrict__ spline_w,
                      const float* __restrict__ scaler,
                      unsigned short* __restrict__ Act,
                      unsigned short* __restrict__ Wb) {
    const int bid = blockIdx.x;
    const int tid = threadIdx.x;
    if (bid < 512) {
        __shared__ float xs[128][65];
        const int mb = bid >> 4;
        const int p  = bid & 15;

        const float* xbase = x + (size_t)mb * 128 * IN_F + p * 64;
        #pragma unroll
        for (int i = 0; i < 32; ++i) {
            const int f = i * 256 + tid;
            const int rr = f >> 6, c = f & 63;
            xs[rr][c] = xbase[(size_t)rr * IN_F + c];
        }
        __syncthreads();

        char* outS = (char*)Act + (size_t)(mb * 144 + p) * 16384;
        char* outB = (char*)Act + (size_t)(mb * 144 + 16 + p * 8) * 16384;

        const float r1 = 1.0f / (0.4f + 1e-8f);
        const float r2 = 1.0f / (0.8f + 1e-8f);
        const float r3 = 1.0f / (1.2f + 1e-8f);

        #pragma unroll
        for (int it = 0; it < 4; ++it) {
            const int ch = it * 256 + tid;
            const int kp = ch >> 9, g = (ch >> 6) & 7, kg = (ch >> 4) & 3, fr = ch & 15;
            const int b = g * 16 + fr;
            const int c0 = kp * 32 + kg * 8;
            short8v v;
            #pragma unroll
            for (int u = 0; u < 8; ++u) {
                const float xv = xs[b][c0 + u];
                v[u] = (short)f2bf(xv * __frcp_rn(1.0f + __expf(-xv)));
            }
            *(short8v*)(outS + kp * 8192 + g * 1024 + kg * 256 + fr * 16) = v;
        }

        #pragma unroll
        for (int it = 0; it < 32; ++it) {
            const int ch  = it * 256 + tid;
            const int ktl = ch >> 10;
            const int rest = ch & 1023;
            const int kp = rest >> 9, g = (rest >> 6) & 7, kg = (rest >> 4) & 3, fr = rest & 15;
            const int b  = g * 16 + fr;
            const int jc = 8 * ktl + 4 * kp + kg;
            const float xv = xs[b][jc];

            float bas[11];
            #pragma unroll
            for (int t = 0; t < 11; ++t)
                bas[t] = (xv >= knot(t) && xv < knot(t + 1)) ? 1.0f : 0.0f;
            #pragma unroll
            for (int t = 0; t < 10; ++t)
                bas[t] = (xv - knot(t)) * r1 * bas[t] + (knot(t + 2) - xv) * r1 * bas[t + 1];
            #pragma unroll
            for (int t = 0; t < 9; ++t)
                bas[t] = (xv - knot(t)) * r2 * bas[t] + (knot(t + 3) - xv) * r2 * bas[t + 1];
            #pragma unroll
            for (int t = 0; t < 8; ++t)
                bas[t] = (xv - knot(t)) * r3 * bas[t] + (knot(t + 4) - xv) * r3 * bas[t + 1];

            short8v v;
            #pragma unroll
            for (int c = 0; c < 8; ++c) v[c] = (short)f2bf(bas[c]);
            *(short8v*)(outB + (size_t)ktl * 16384
                        + kp * 8192 + g * 1024 + kg * 256 + fr * 16) = v;
        }
    } else if (bid < 1024) {
        const int bw = bid - 512;
        const int nb = bw >> 6, kt = (bw >> 1) & 31, half = bw & 1;
        const int g = half * 4 + (tid >> 6);
        const int lane = tid & 63;
        const int kgrp = lane >> 4, frow = lane & 15;
        const int oo = nb * 128 + g * 16 + frow;
        const int jb = kt * 32 + kgrp * 8;

        const float4 w0 = *(const float4*)(base_w + (size_t)oo * 1024 + jb);
        const float4 w1 = *(const float4*)(base_w + (size_t)oo * 1024 + jb + 4);
        short8v v;
        v[0] = (short)f2bf(w0.x); v[1] = (short)f2bf(w0.y);
        v[2] = (short)f2bf(w0.z); v[3] = (short)f2bf(w0.w);
        v[4] = (short)f2bf(w1.x); v[5] = (short)f2bf(w1.y);
        v[6] = (short)f2bf(w1.z); v[7] = (short)f2bf(w1.w);
        *(short8v*)((char*)Wb + (size_t)(nb * NTK + kt) * PSTEP
                    + g * 1024 + lane * 16) = v;
    } else {
        const int bw = bid - 1024;
        const int nb = bw >> 9, kt2 = (bw >> 1) & 255, half = bw & 1;
        const int kt = 32 + kt2;
        const int g = half * 4 + (tid >> 6);
        const int lane = tid & 63;
        const int kgrp = lane >> 4, frow = lane & 15;
        const int oo = nb * 128 + g * 16 + frow;
        const int j  = kt2 * 4 + kgrp;

        const float s = scaler[(size_t)oo * 1024 + j];
        const float* sp = spline_w + ((size_t)oo * 1024 + j) * 8;
        const float4 w0 = *(const float4*)sp;
        const float4 w1 = *(const float4*)(sp + 4);
        short8v v;
        v[0] = (short)f2bf(w0.x * s); v[1] = (short)f2bf(w0.y * s);
        v[2] = (short)f2bf(w0.z * s); v[3] = (short)f2bf(w0.w * s);
        v[4] = (short)f2bf(w1.x * s); v[5] = (short)f2bf(w1.y * s);
        v[6] = (short)f2bf(w1.z * s); v[7] = (short)f2bf(w1.w * s);
        *(short8v*)((char*)Wb + (size_t)(nb * NTK + kt) * PSTEP
                    + g * 1024 + lane * 16) = v;
    }
}

// ---------------------------------------------------------------------------
// 256x256 GEMM, BK=32, adaptive split-K. r12 + sched_barrier(0)-FENCED
// interleave: region = RD_A(next) |f| 16 MFMA(cur) |f| RD_B(next) |f|
// 16 MFMA(cur). r12's prefetch was undone by the compiler (ds_reads sunk to
// just-before-use, re-serializing DS->MFMA; VGPR=120 evidence). Fences pin
// the reads above MFMA bursts that don't consume them; operand waits become
// counted lgkmcnt(4/12) per compiler norm (m97 asm evidence), so the DS pipe
// (~1100 cyc/step) drains under the MFMA pipe (1242 cyc/step).
// vmcnt/ring/barrier schedule identical to r12.
// ---------------------------------------------------------------------------
__global__ __launch_bounds__(512)
void gemm_kernel(const unsigned short* __restrict__ Act,
                 const unsigned short* __restrict__ Wb,
                 float* __restrict__ C, float* __restrict__ P,
                 int ksteps) {
    __shared__ char Sm[4 * SLOT_B];   // 128 KB

    const int tid  = threadIdx.x;
    const int lane = tid & 63;
    const int wave = tid >> 6;
    const int wr   = wave >> 1;       // 0..3 (64-row slice)
    const int wn   = wave & 1;        // 0..1 (128-col half)

    const int bid  = blockIdx.x;
    const int xcd  = bid & 7;
    const int rr_  = bid >> 3;
    const int mtile = xcd * 2 + (rr_ & 1);   // A panels XCD-private
    const int ntile = (rr_ >> 1) & 3;
    const int s     = rr_ >> 3;              // split-K index

    const int frow = lane & 15;
    const int kgrp = lane >> 4;

    float* Cout = (s == 0) ? C : (P + (size_t)(s - 1) * ((size_t)BATCH * OUT_F));

    f32x4 acc[4][8] = {};             // accumulators
    bf16x8 aR0[4], bR0[8], aR1[4], bR1[8];   // frag double-buffer

    const int o = tid * 16;
    const size_t ktbase = (size_t)s * ksteps;

    const char* aLo = (const char*)Act + ((size_t)(mtile * 2) * NTK + ktbase) * PSTEP + o;
    const char* aHi = aLo + (size_t)NTK * PSTEP;
    const char* bLo = (const char*)Wb  + ((size_t)(ntile * 2) * NTK + ktbase) * PSTEP + o;
    const char* bHi = bLo + (size_t)NTK * PSTEP;

    #define STAGE(kt, sl) do {                                       \
        const size_t kk = (size_t)(kt) * PSTEP;                      \
        char* d = Sm + (size_t)(sl) * SLOT_B + o;                    \
        gl_lds16(aLo + kk, d);                                       \
        gl_lds16(aHi + kk, d + 8192);                                \
        gl_lds16(bLo + kk, d + 16384);                               \
        gl_lds16(bHi + kk, d + 24576);                               \
    } while (0)

    #define RD_A(sl, AB) do {                                                 \
        const char* bA_ = Sm + (size_t)(sl) * SLOT_B;                         \
        _Pragma("unroll")                                                     \
        for (int m = 0; m < 4; ++m)                                           \
            (AB)[m] = *(const bf16x8*)(bA_ + (wr * 4 + m) * 1024 + lane * 16);\
    } while (0)

    #define RD_B(sl, BB) do {                                                 \
        const char* bB_ = Sm + (size_t)(sl) * SLOT_B + 16384;                 \
        _Pragma("unroll")                                                     \
        for (int n = 0; n < 8; ++n)                                           \
            (BB)[n] = *(const bf16x8*)(bB_ + (wn * 8 + n) * 1024 + lane * 16);\
    } while (0)

    #define MFMA_ROWS(AB, BB, M0_, M1_) do {                                  \
        __builtin_amdgcn_s_setprio(1);                                        \
        _Pragma("unroll")                                                     \
        for (int m = (M0_); m < (M1_); ++m)                                   \
            _Pragma("unroll")                                                 \
            for (int n = 0; n < 8; ++n)                                       \
                acc[m][n] = __builtin_amdgcn_mfma_f32_16x16x32_bf16(          \
                                (AB)[m], (BB)[n], acc[m][n], 0, 0, 0);        \
        __builtin_amdgcn_s_setprio(0);                                        \
    } while (0)

    #define FENCE __builtin_amdgcn_sched_barrier(0)

    #define SYNC(VM) do {                                                     \
        asm volatile("s_waitcnt vmcnt(" #VM ")" ::: "memory");                \
        __builtin_amdgcn_s_barrier();                                         \
        FENCE;                                                                \
    } while (0)

    // region: prefetch tile in slot sl into (An,Bn); MFMA on (Ac,Bc)
    #define BODY(sl, Ac, Bc, An, Bn) do {                                     \
        RD_A((sl), An);                                                       \
        FENCE;                                                                \
        MFMA_ROWS(Ac, Bc, 0, 2);                                              \
        FENCE;                                                                \
        RD_B((sl), Bn);                                                       \
        FENCE;                                                                \
        MFMA_ROWS(Ac, Bc, 2, 4);                                              \
        FENCE;                                                                \
    } while (0)

    // ---- prologue: tiles 0,1 staged; land tile 0; preload its frags -------
    STAGE(0, 0);
    STAGE(1, 1);
    SYNC(4);                        // tile 0 landed (tile 1 outstanding)
    RD_A(0, aR0); RD_B(0, bR0);

    // ---- main: 2-step unrolled; kt = 0,2,..,ksteps-4 ----------------------
    #pragma unroll 1
    for (int kt = 0; kt < ksteps - 2; kt += 2) {
        STAGE(kt + 2, (kt + 2) & 3);
        SYNC(4);                    // tile kt+1 landed
        BODY((kt + 1) & 3, aR0, bR0, aR1, bR1);   // compute kt, prefetch kt+1

        STAGE(kt + 3, (kt + 3) & 3);
        SYNC(4);                    // tile kt+2 landed
        BODY((kt + 2) & 3, aR1, bR1, aR0, bR0);   // compute kt+1, prefetch kt+2
    }

    // ---- tail: tiles ksteps-2, ksteps-1 (aR0 holds ksteps-2 frags) --------
    SYNC(0);                        // tile ksteps-1 landed
    BODY((ksteps - 1) & 3, aR0, bR0, aR1, bR1);   // compute ksteps-2
    MFMA_ROWS(aR1, bR1, 0, 4);                    // compute ksteps-1

    // ---- epilogue: direct store; C/D map col=lane&15, row=(lane>>4)*4+reg --
    const int m0 = mtile * BM, n0 = ntile * BN;
    #pragma unroll
    for (int m = 0; m < 4; ++m) {
        const int row = m0 + wr * 64 + m * 16 + kgrp * 4;
        #pragma unroll
        for (int n = 0; n < 8; ++n) {
            const int col = n0 + wn * 128 + n * 16 + frow;
            float* cp = Cout + (size_t)row * OUT_F + col;
            #pragma unroll
            for (int q = 0; q < 4; ++q)
                cp[(size_t)q * OUT_F] = acc[m][n][q];
        }
    }
    #undef STAGE
    #undef RD_A
    #undef RD_B
    #undef MFMA_ROWS
    #undef FENCE
    #undef SYNC
    #undef BODY
}

// ---------------------------------------------------------------------------
__global__ __launch_bounds__(256)
void add_kernel(float* __restrict__ out, const float* __restrict__ P, int np) {
    const size_t i = (size_t)blockIdx.x * 256 + threadIdx.x;   // float4 index
    float4 a = ((const float4*)out)[i];
    for (int k = 0; k < np; ++k) {
        float4 b = ((const float4*)(P + (size_t)k * ((size_t)BATCH * OUT_F)))[i];
        a.x += b.x; a.y += b.y; a.z += b.z; a.w += b.w;
    }
    ((float4*)out)[i] = a;
}

// ---------------------------------------------------------------------------
extern "C" void kernel_launch(void* const* d_in, const int* in_sizes, int n_in,
                              void* d_out, int out_size, void* d_ws, size_t ws_size,
                              hipStream_t stream) {
    const float* x        = (const float*)d_in[0];
    const float* base_w   = (const float*)d_in[1];
    const float* spline_w = (const float*)d_in[2];
    const float* scaler   = (const float*)d_in[3];
    float* out = (float*)d_out;

    const size_t act_b = (size_t)BATCH * KTOT * 2;        // 75.5 MB
    const size_t wb_b  = (size_t)OUT_F * KTOT * 2;        // 18.9 MB
    const size_t ps    = (size_t)BATCH * OUT_F * 4;       // 16.8 MB per partial
    if (ws_size < act_b + wb_b) return;

    unsigned short* Act = (unsigned short*)d_ws;
    unsigned short* Wb  = (unsigned short*)((char*)d_ws + act_b);
    float*          P   = (float*)((char*)d_ws + act_b + wb_b);

    size_t avail = ws_size - act_b - wb_b;
    int np = (int)(avail / ps); if (np > 3) np = 3; if (np < 0) np = 0;
    const int nsplit = np + 1;             // 1,2,3,4 all divide 288
    const int ksteps = NTK / nsplit;

    build_all_kernel<<<5120, 256, 0, stream>>>(x, base_w, spline_w, scaler, Act, Wb);
    gemm_kernel<<<64 * nsplit, 512, 0, stream>>>(Act, Wb, out, P, ksteps);
    if (np > 0)
        add_kernel<<<(BATCH * OUT_F) / (256 * 4), 256, 0, stream>>>(out, P, np);
}

// Round 14
// 112.372 us; speedup vs baseline: 1.0498x; 1.0086x over previous
//
#include <hip/hip_runtime.h>
#include <hip/hip_bf16.h>
#include <cstdint>

#define IN_F   1024
#define OUT_F  1024
#define KTOT   9216
#define BATCH  4096

#define NTK    288            // total BK=32 K-steps
#define PSTEP  8192           // bytes per (128-row panel, kt32) fragment block
#define BSLOT  16384          // B ring slot: 256 cols x 32 k x 2B
#define BM 256
#define BN 256

typedef __attribute__((ext_vector_type(8))) __bf16 bf16x8;
typedef __attribute__((ext_vector_type(4))) float  f32x4;
typedef __attribute__((ext_vector_type(8))) short  short8v;

typedef __attribute__((address_space(1))) const uint32_t gu32;
typedef __attribute__((address_space(3))) uint32_t       lu32;

__device__ __forceinline__ void gl_lds16(const void* g, void* l) {
    __builtin_amdgcn_global_load_lds((gu32*)g, (lu32*)l, 16, 0, 0);
}

__device__ __forceinline__ unsigned short f2bf(float f) {
    unsigned int u = __builtin_bit_cast(unsigned int, f);
    return (unsigned short)((u + 0x7fffu + ((u >> 16) & 1u)) >> 16);
}

__device__ __forceinline__ float knot(int i) { return 0.4f * (float)i - 2.2f; }

// ---------------------------------------------------------------------------
// Fragment-major layout (both Act and Wb):
//   byte = ((panel128 * 288 + kt32) * 8192) + g*1024 + (kgrp*16 + frow)*16
// One 1KB unit = one MFMA fragment (64 lanes x 16B, contiguous).
// ---------------------------------------------------------------------------

// ---------------------------------------------------------------------------
// Prep (r10-verbatim). [0,512): Act. [512,1024): Wb base. [1024,5120): spline.
// ---------------------------------------------------------------------------
__global__ __launch_bounds__(256)
void build_all_kernel(const float* __restrict__ x,
                      const float* __restrict__ base_w,
                      const float* __restrict__ spline_w,
                      const float* __restrict__ scaler,
                      unsigned short* __restrict__ Act,
                      unsigned short* __restrict__ Wb) {
    const int bid = blockIdx.x;
    const int tid = threadIdx.x;
    if (bid < 512) {
        __shared__ float xs[128][65];
        const int mb = bid >> 4;
        const int p  = bid & 15;

        const float* xbase = x + (size_t)mb * 128 * IN_F + p * 64;
        #pragma unroll
        for (int i = 0; i < 32; ++i) {
            const int f = i * 256 + tid;
            const int rr = f >> 6, c = f & 63;
            xs[rr][c] = xbase[(size_t)rr * IN_F + c];
        }
        __syncthreads();

        char* outS = (char*)Act + (size_t)(mb * 144 + p) * 16384;
        char* outB = (char*)Act + (size_t)(mb * 144 + 16 + p * 8) * 16384;

        const float r1 = 1.0f / (0.4f + 1e-8f);
        const float r2 = 1.0f / (0.8f + 1e-8f);
        const float r3 = 1.0f / (1.2f + 1e-8f);

        #pragma unroll
        for (int it = 0; it < 4; ++it) {
            const int ch = it * 256 + tid;
            const int kp = ch >> 9, g = (ch >> 6) & 7, kg = (ch >> 4) & 3, fr = ch & 15;
            const int b = g * 16 + fr;
            const int c0 = kp * 32 + kg * 8;
            short8v v;
            #pragma unroll
            for (int u = 0; u < 8; ++u) {
                const float xv = xs[b][c0 + u];
                v[u] = (short)f2bf(xv * __frcp_rn(1.0f + __expf(-xv)));
            }
            *(short8v*)(outS + kp * 8192 + g * 1024 + kg * 256 + fr * 16) = v;
        }

        #pragma unroll
        for (int it = 0; it < 32; ++it) {
            const int ch  = it * 256 + tid;
            const int ktl = ch >> 10;
            const int rest = ch & 1023;
            const int kp = rest >> 9, g = (rest >> 6) & 7, kg = (rest >> 4) & 3, fr = rest & 15;
            const int b  = g * 16 + fr;
            const int jc = 8 * ktl + 4 * kp + kg;
            const float xv = xs[b][jc];

            float bas[11];
            #pragma unroll
            for (int t = 0; t < 11; ++t)
                bas[t] = (xv >= knot(t) && xv < knot(t + 1)) ? 1.0f : 0.0f;
            #pragma unroll
            for (int t = 0; t < 10; ++t)
                bas[t] = (xv - knot(t)) * r1 * bas[t] + (knot(t + 2) - xv) * r1 * bas[t + 1];
            #pragma unroll
            for (int t = 0; t < 9; ++t)
                bas[t] = (xv - knot(t)) * r2 * bas[t] + (knot(t + 3) - xv) * r2 * bas[t + 1];
            #pragma unroll
            for (int t = 0; t < 8; ++t)
                bas[t] = (xv - knot(t)) * r3 * bas[t] + (knot(t + 4) - xv) * r3 * bas[t + 1];

            short8v v;
            #pragma unroll
            for (int c = 0; c < 8; ++c) v[c] = (short)f2bf(bas[c]);
            *(short8v*)(outB + (size_t)ktl * 16384
                        + kp * 8192 + g * 1024 + kg * 256 + fr * 16) = v;
        }
    } else if (bid < 1024) {
        const int bw = bid - 512;
        const int nb = bw >> 6, kt = (bw >> 1) & 31, half = bw & 1;
        const int g = half * 4 + (tid >> 6);
        const int lane = tid & 63;
        const int kgrp = lane >> 4, frow = lane & 15;
        const int oo = nb * 128 + g * 16 + frow;
        const int jb = kt * 32 + kgrp * 8;

        const float4 w0 = *(const float4*)(base_w + (size_t)oo * 1024 + jb);
        const float4 w1 = *(const float4*)(base_w + (size_t)oo * 1024 + jb + 4);
        short8v v;
        v[0] = (short)f2bf(w0.x); v[1] = (short)f2bf(w0.y);
        v[2] = (short)f2bf(w0.z); v[3] = (short)f2bf(w0.w);
        v[4] = (short)f2bf(w1.x); v[5] = (short)f2bf(w1.y);
        v[6] = (short)f2bf(w1.z); v[7] = (short)f2bf(w1.w);
        *(short8v*)((char*)Wb + (size_t)(nb * NTK + kt) * PSTEP
                    + g * 1024 + lane * 16) = v;
    } else {
        const int bw = bid - 1024;
        const int nb = bw >> 9, kt2 = (bw >> 1) & 255, half = bw & 1;
        const int kt = 32 + kt2;
        const int g = half * 4 + (tid >> 6);
        const int lane = tid & 63;
        const int kgrp = lane >> 4, frow = lane & 15;
        const int oo = nb * 128 + g * 16 + frow;
        const int j  = kt2 * 4 + kgrp;

        const float s = scaler[(size_t)oo * 1024 + j];
        const float* sp = spline_w + ((size_t)oo * 1024 + j) * 8;
        const float4 w0 = *(const float4*)sp;
        const float4 w1 = *(const float4*)(sp + 4);
        short8v v;
        v[0] = (short)f2bf(w0.x * s); v[1] = (short)f2bf(w0.y * s);
        v[2] = (short)f2bf(w0.z * s); v[3] = (short)f2bf(w0.w * s);
        v[4] = (short)f2bf(w1.x * s); v[5] = (short)f2bf(w1.y * s);
        v[6] = (short)f2bf(w1.z * s); v[7] = (short)f2bf(w1.w * s);
        *(short8v*)((char*)Wb + (size_t)(nb * NTK + kt) * PSTEP
                    + g * 1024 + lane * 16) = v;
    }
}

// ---------------------------------------------------------------------------
// 256x256 GEMM, BK=32, adaptive split-K. Three-pipe split (r13 showed the
// LDS pipe itself >= MFMA time, so scheduling could never win):
//   A: fragment-major direct G->VGPR (1KB contiguous bursts), dbuf 1 ahead.
//   B: LDS ring-4 (16KB slots), reg-prefetched frags 1 step ahead.
//   LDS/step: 64 reads + 16KB writes ~= 960 cyc; VMEM 48KB ~= 750 cyc;
//   MFMA 1242 cyc -> MFMA is the floor.
// 8 waves = 4(M) x 2(N), wave tile 64x128, acc 4x8.
// vmcnt: each region issues 4 A-loads then 2 B-stages; vmcnt(6) drains the
// previous region's 6 (A(kt) regs ready, slot kt+2 landed). Stage depth 3,
// ring 4: slot s is read (region s-1) and its reads are lgkm-drained by the
// MFMA in region s, >= 1 full region + write latency before the next write
// to slot s (issued region s+1) can land.
// ---------------------------------------------------------------------------
__global__ __launch_bounds__(512)
void gemm_kernel(const unsigned short* __restrict__ Act,
                 const unsigned short* __restrict__ Wb,
                 float* __restrict__ C, float* __restrict__ P,
                 int ksteps) {
    __shared__ char Sm[4 * BSLOT];   // 64 KB B-ring

    const int tid  = threadIdx.x;
    const int lane = tid & 63;
    const int wave = tid >> 6;
    const int wr   = wave >> 1;       // 0..3: 64-row slice
    const int wn   = wave & 1;        // 0..1: 128-col half

    const int bid  = blockIdx.x;
    const int xcd  = bid & 7;
    const int rr_  = bid >> 3;
    const int mtile = xcd * 2 + (rr_ & 1);   // A panels XCD-private
    const int ntile = (rr_ >> 1) & 3;
    const int s     = rr_ >> 3;              // split-K index

    const int frow = lane & 15;
    const int kgrp = lane >> 4;

    float* Cout = (s == 0) ? C : (P + (size_t)(s - 1) * ((size_t)BATCH * OUT_F));

    f32x4 acc[4][8] = {};             // 128 accumulator regs
    bf16x8 aR0[4], aR1[4], bR0[8], bR1[8];

    const int o = tid * 16;
    const size_t ktbase = (size_t)s * ksteps;

    // ---- A direct: wave's 4 frags = one 4KB contiguous burst per kt --------
    const int apanel = mtile * 2 + (wr >> 1);
    const char* aBase = (const char*)Act
        + ((size_t)apanel * NTK + ktbase) * PSTEP
        + ((wr & 1) * 4) * 1024 + lane * 16;

    #define LOADA(kt, AB) do {                                       \
        const char* p_ = aBase + (size_t)(kt) * PSTEP;               \
        _Pragma("unroll")                                            \
        for (int m = 0; m < 4; ++m)                                  \
            (AB)[m] = *(const bf16x8*)(p_ + m * 1024);               \
    } while (0)

    // ---- B staging: slot = [panelLo 8KB | panelHi 8KB] ---------------------
    const char* bLo = (const char*)Wb + ((size_t)(ntile * 2) * NTK + ktbase) * PSTEP + o;
    const char* bHi = bLo + (size_t)NTK * PSTEP;

    #define STAGEB(kt, sl) do {                                      \
        const size_t kk = (size_t)(kt) * PSTEP;                      \
        char* d = Sm + (size_t)(sl) * BSLOT + o;                     \
        gl_lds16(bLo + kk, d);                                       \
        gl_lds16(bHi + kk, d + 8192);                                \
    } while (0)

    // ---- B frag read: idx = wn*8+n -> 1KB contiguous, conflict-free --------
    #define RD_B(sl, BB) do {                                                 \
        const char* b_ = Sm + (size_t)(sl) * BSLOT + wn * 8192 + lane * 16;   \
        _Pragma("unroll")                                                     \
        for (int n = 0; n < 8; ++n)                                           \
            (BB)[n] = *(const bf16x8*)(b_ + n * 1024);                        \
    } while (0)

    #define MFMA32(AB, BB) do {                                               \
        __builtin_amdgcn_s_setprio(1);                                        \
        _Pragma("unroll")                                                     \
        for (int m = 0; m < 4; ++m)                                           \
            _Pragma("unroll")                                                 \
            for (int n = 0; n < 8; ++n)                                       \
                acc[m][n] = __builtin_amdgcn_mfma_f32_16x16x32_bf16(          \
                                (AB)[m], (BB)[n], acc[m][n], 0, 0, 0);        \
        __builtin_amdgcn_s_setprio(0);                                        \
    } while (0)

    #define FENCE __builtin_amdgcn_sched_barrier(0)

    // region kt: LA(kt+1); SB(kt+3); vmcnt(6); bar; RD_B(kt+1); MFMA(kt)
    #define REGION(kt, Ac, An, Bc, Bn, SB_ON, VM) do {                        \
        LOADA((kt) + 1, An);                                                  \
        if (SB_ON) STAGEB((kt) + 3, ((kt) + 3) & 3);                          \
        asm volatile("s_waitcnt vmcnt(" #VM ")" ::: "memory");                \
        __builtin_amdgcn_s_barrier();                                         \
        FENCE;                                                                \
        RD_B(((kt) + 1) & 3, Bn);                                             \
        FENCE;                                                                \
        MFMA32(Ac, Bc);                                                       \
        FENCE;                                                                \
    } while (0)

    // ---- prologue: SB(0..2), LA(0); land slot0; read B(0) frags -----------
    STAGEB(0, 0);                     // 2 vm
    STAGEB(1, 1);                     // 2
    STAGEB(2, 2);                     // 2
    LOADA(0, aR0);                    // 4   (10 outstanding)
    asm volatile("s_waitcnt vmcnt(8)" ::: "memory");   // slot0 landed
    __builtin_amdgcn_s_barrier();
    FENCE;
    RD_B(0, bR0);
    FENCE;

    // ---- main: regions kt = 0 .. ksteps-5 (pairs; ksteps even) ------------
    #pragma unroll 1
    for (int kt = 0; kt < ksteps - 4; kt += 2) {
        REGION(kt,     aR0, aR1, bR0, bR1, 1, 6);
        REGION(kt + 1, aR1, aR0, bR1, bR0, 1, 6);
    }

    // ---- tail: regions ksteps-4 .. ksteps-1 (parity: ksteps-4 even) -------
    REGION(ksteps - 4, aR0, aR1, bR0, bR1, 1, 6);   // stages slot ksteps-1
    REGION(ksteps - 3, aR1, aR0, bR1, bR0, 0, 4);
    REGION(ksteps - 2, aR0, aR1, bR0, bR1, 0, 4);
    // region ksteps-1: no LA/SB
    asm volatile("s_waitcnt vmcnt(0)" ::: "memory");
    MFMA32(aR1, bR1);

    // ---- epilogue: direct store; C/D map col=lane&15, row=(lane>>4)*4+reg --
    const int m0 = mtile * BM, n0 = ntile * BN;
    #pragma unroll
    for (int m = 0; m < 4; ++m) {
        const int row = m0 + wr * 64 + m * 16 + kgrp * 4;
        #pragma unroll
        for (int n = 0; n < 8; ++n) {
            const int col = n0 + wn * 128 + n * 16 + frow;
            float* cp = Cout + (size_t)row * OUT_F + col;
            #pragma unroll
            for (int q = 0; q < 4; ++q)
                cp[(size_t)q * OUT_F] = acc[m][n][q];
        }
    }
    #undef LOADA
    #undef STAGEB
    #undef RD_B
    #undef MFMA32
    #undef FENCE
    #undef REGION
}

// ---------------------------------------------------------------------------
__global__ __launch_bounds__(256)
void add_kernel(float* __restrict__ out, const float* __restrict__ P, int np) {
    const size_t i = (size_t)blockIdx.x * 256 + threadIdx.x;   // float4 index
    float4 a = ((const float4*)out)[i];
    for (int k = 0; k < np; ++k) {
        float4 b = ((const float4*)(P + (size_t)k * ((size_t)BATCH * OUT_F)))[i];
        a.x += b.x; a.y += b.y; a.z += b.z; a.w += b.w;
    }
    ((float4*)out)[i] = a;
}

// ---------------------------------------------------------------------------
extern "C" void kernel_launch(void* const* d_in, const int* in_sizes, int n_in,
                              void* d_out, int out_size, void* d_ws, size_t ws_size,
                              hipStream_t stream) {
    const float* x        = (const float*)d_in[0];
    const float* base_w   = (const float*)d_in[1];
    const float* spline_w = (const float*)d_in[2];
    const float* scaler   = (const float*)d_in[3];
    float* out = (float*)d_out;

    const size_t act_b = (size_t)BATCH * KTOT * 2;        // 75.5 MB
    const size_t wb_b  = (size_t)OUT_F * KTOT * 2;        // 18.9 MB
    const size_t ps    = (size_t)BATCH * OUT_F * 4;       // 16.8 MB per partial
    if (ws_size < act_b + wb_b) return;

    unsigned short* Act = (unsigned short*)d_ws;
    unsigned short* Wb  = (unsigned short*)((char*)d_ws + act_b);
    float*          P   = (float*)((char*)d_ws + act_b + wb_b);

    size_t avail = ws_size - act_b - wb_b;
    int np = (int)(avail / ps); if (np > 3) np = 3; if (np < 0) np = 0;
    const int nsplit = np + 1;             // 1,2,3,4 all divide 288
    const int ksteps = NTK / nsplit;

    build_all_kernel<<<5120, 256, 0, stream>>>(x, base_w, spline_w, scaler, Act, Wb);
    gemm_kernel<<<64 * nsplit, 512, 0, stream>>>(Act, Wb, out, P, ksteps);
    if (np > 0)
        add_kernel<<<(BATCH * OUT_F) / (256 * 4), 256, 0, stream>>>(out, P, np);
}